// Round 1
// baseline (375.656 us; speedup 1.0000x reference)
//
#include <hip/hip_runtime.h>
#include <stdint.h>

#define N_MODELC 1024
#define KV_MODELC 256
#define BATCH 4
#define SEQ 2048
#define NTOK (BATCH*SEQ)   // 8192

typedef __attribute__((ext_vector_type(4))) float f32x4;
typedef __attribute__((ext_vector_type(4))) int   i32x4;
typedef __attribute__((ext_vector_type(8))) short s16x8;

__device__ __forceinline__ unsigned short f2bf(float f){
  unsigned u = __builtin_bit_cast(unsigned, f);
  u = (u + 0x7FFFu + ((u>>16)&1u)) >> 16;
  return (unsigned short)u;
}

// ---------------- activation rmsnorm + int8 absmax quant (1024-wide rows) ----
__global__ __launch_bounds__(256) void k_actquant1024(
    const float* __restrict__ xq_in, const float* __restrict__ xk_in, const float* __restrict__ xv_in,
    int8_t* __restrict__ q8q, int8_t* __restrict__ q8k, int8_t* __restrict__ q8v,
    float* __restrict__ scq, float* __restrict__ sck, float* __restrict__ scv)
{
  int row = blockIdx.x, which = blockIdx.y, t = threadIdx.x;
  const float* x = (which==0)?xq_in:(which==1)?xk_in:xv_in;
  int8_t* q8 = (which==0)?q8q:(which==1)?q8k:q8v;
  float* sc = (which==0)?scq:(which==1)?sck:scv;
  const float* xr = x + (size_t)row*N_MODELC;
  float4 v = reinterpret_cast<const float4*>(xr)[t];
  float ss = v.x*v.x + v.y*v.y + v.z*v.z + v.w*v.w;
  float am = fmaxf(fmaxf(fabsf(v.x),fabsf(v.y)), fmaxf(fabsf(v.z),fabsf(v.w)));
  #pragma unroll
  for (int m=32;m;m>>=1){ ss += __shfl_xor(ss,m,64); am = fmaxf(am, __shfl_xor(am,m,64)); }
  __shared__ float red[8];
  int wid = t>>6;
  if ((t&63)==0){ red[wid]=ss; red[4+wid]=am; }
  __syncthreads();
  ss = red[0]+red[1]+red[2]+red[3];
  am = fmaxf(fmaxf(red[4],red[5]), fmaxf(red[6],red[7]));
  float rinv = rsqrtf(ss*(1.0f/N_MODELC) + 1e-6f);
  float clipv = fmaxf(am*rinv, 1e-5f);
  float qs = 127.0f/clipv;
  float fsc = rinv*qs;
  char4 o;
  o.x = (signed char)(int)fminf(127.f, fmaxf(-128.f, rintf(v.x*fsc)));
  o.y = (signed char)(int)fminf(127.f, fmaxf(-128.f, rintf(v.y*fsc)));
  o.z = (signed char)(int)fminf(127.f, fmaxf(-128.f, rintf(v.z*fsc)));
  o.w = (signed char)(int)fminf(127.f, fmaxf(-128.f, rintf(v.w*fsc)));
  reinterpret_cast<char4*>(q8 + (size_t)row*N_MODELC)[t] = o;
  if (t==0) sc[row] = clipv*(1.0f/127.0f);
}

// ---------------- same for 256-wide rows (one wave per row) ------------------
__global__ __launch_bounds__(64) void k_actquant256(
    const float* __restrict__ X, int8_t* __restrict__ q8, float* __restrict__ sc)
{
  int row = blockIdx.x, l = threadIdx.x;
  float4 v = reinterpret_cast<const float4*>(X + (size_t)row*KV_MODELC)[l];
  float ss = v.x*v.x + v.y*v.y + v.z*v.z + v.w*v.w;
  float am = fmaxf(fmaxf(fabsf(v.x),fabsf(v.y)), fmaxf(fabsf(v.z),fabsf(v.w)));
  #pragma unroll
  for (int m=32;m;m>>=1){ ss += __shfl_xor(ss,m,64); am = fmaxf(am, __shfl_xor(am,m,64)); }
  float rinv = rsqrtf(ss*(1.0f/KV_MODELC) + 1e-6f);
  float clipv = fmaxf(am*rinv, 1e-5f);
  float qs = 127.0f/clipv;
  float fsc = rinv*qs;
  char4 o;
  o.x = (signed char)(int)fminf(127.f, fmaxf(-128.f, rintf(v.x*fsc)));
  o.y = (signed char)(int)fminf(127.f, fmaxf(-128.f, rintf(v.y*fsc)));
  o.z = (signed char)(int)fminf(127.f, fmaxf(-128.f, rintf(v.z*fsc)));
  o.w = (signed char)(int)fminf(127.f, fmaxf(-128.f, rintf(v.w*fsc)));
  reinterpret_cast<char4*>(q8 + (size_t)row*KV_MODELC)[l] = o;
  if (l==0) sc[row] = clipv*(1.0f/127.0f);
}

// ---------------- weight absmean: stage 1 (deterministic partials) -----------
__global__ __launch_bounds__(256) void k_wabs_partial(
    const float* __restrict__ Wq, const float* __restrict__ Wk,
    const float* __restrict__ Wv, const float* __restrict__ Wo, float* __restrict__ partial)
{
  int mat = blockIdx.y;
  const float* w = (mat==0)?Wq:(mat==1)?Wk:(mat==2)?Wv:Wo;
  int n = (mat==0)?(N_MODELC*N_MODELC):(KV_MODELC*N_MODELC);
  float s = 0.f;
  for (int i = blockIdx.x*256 + threadIdx.x; i < n; i += 256*256) s += fabsf(w[i]);
  #pragma unroll
  for (int m=32;m;m>>=1) s += __shfl_xor(s,m,64);
  __shared__ float red[4];
  int wid = threadIdx.x>>6;
  if ((threadIdx.x&63)==0) red[wid]=s;
  __syncthreads();
  if (threadIdx.x==0) partial[mat*256 + blockIdx.x] = red[0]+red[1]+red[2]+red[3];
}

// ---------------- weight absmean: stage 2 ------------------------------------
__global__ __launch_bounds__(256) void k_wfinal(const float* __restrict__ partial, float* __restrict__ wfac)
{
  int mat = blockIdx.x, t = threadIdx.x;
  float s = partial[mat*256 + t];
  #pragma unroll
  for (int m=32;m;m>>=1) s += __shfl_xor(s,m,64);
  __shared__ float red[4];
  int wid = t>>6;
  if ((t&63)==0) red[wid]=s;
  __syncthreads();
  if (t==0){
    float tot = red[0]+red[1]+red[2]+red[3];
    float n = (mat==0)?(float)(N_MODELC*N_MODELC):(float)(KV_MODELC*N_MODELC);
    wfac[mat] = fmaxf(tot/n, 1e-5f);   // = 1/scale (dequant factor)
  }
}

// ---------------- ternarize weights (Wq also group-summed) -------------------
__global__ __launch_bounds__(256) void k_tern(
    const float* __restrict__ Wq, const float* __restrict__ Wk,
    const float* __restrict__ Wv, const float* __restrict__ Wo,
    const float* __restrict__ wfac,
    int8_t* __restrict__ Wqs, int8_t* __restrict__ Wkt,
    int8_t* __restrict__ Wvt, int8_t* __restrict__ Wot)
{
  int mat = blockIdx.y;
  int idx = blockIdx.x*256 + threadIdx.x;   // < 262144
  if (mat==0){
    float s = 1.0f/wfac[0];
    int op = idx>>10, i = idx&1023;
    int kv = op>>6, d = op&63;
    int acc = 0;
    #pragma unroll
    for (int g=0; g<4; g++){
      float w = Wq[(size_t)(kv*256 + g*64 + d)*N_MODELC + i];
      float r = fminf(1.f, fmaxf(-1.f, rintf(w*s)));
      acc += (int)r;
    }
    Wqs[idx] = (int8_t)acc;
  } else {
    const float* w = (mat==1)?Wk:(mat==2)?Wv:Wo;
    int8_t* o = (mat==1)?Wkt:(mat==2)?Wvt:Wot;
    float s = 1.0f/wfac[mat];
    float r = fminf(1.f, fmaxf(-1.f, rintf(w[idx]*s)));
    o[idx] = (int8_t)r;
  }
}

// ---------------- int8 GEMM: C = A[M,K] x B[N,K]^T, dequant epilogue ---------
// MODE 0: Qsum -> bf16 [M,256], x0.125, group-summed bias
// MODE 1: K    -> bf16 [M,256]
// MODE 2: V    -> bf16 transposed VT[(b*256+col), s]
// MODE 3: O    -> f32 [M,1024] to d_out
template<int KDIM, int MODE>
__global__ __launch_bounds__(256) void k_gemm_i8(
    const int8_t* __restrict__ A, const int8_t* __restrict__ B,
    const float* __restrict__ rowscale, const float* __restrict__ wfac, int wfi,
    const float* __restrict__ bias, void* __restrict__ outp)
{
  int mb = blockIdx.x*64, nb = blockIdx.y*64;
  int w = threadIdx.x>>6, l = threadIdx.x&63, lr = l&15, lk = l>>4;
  const int8_t* Ap = A + (size_t)(mb + w*16 + lr)*KDIM + lk*16;
  const int8_t* Bp = B + (size_t)(nb + lr)*KDIM + lk*16;
  i32x4 acc[4];
  #pragma unroll
  for (int f=0; f<4; f++) acc[f] = i32x4{0,0,0,0};
  #pragma unroll 4
  for (int kk=0; kk<KDIM; kk+=64){
    i32x4 a = *reinterpret_cast<const i32x4*>(Ap + kk);
    #pragma unroll
    for (int f=0; f<4; f++){
      i32x4 b = *reinterpret_cast<const i32x4*>(Bp + (size_t)f*16*KDIM + kk);
      acc[f] = __builtin_amdgcn_mfma_i32_16x16x64_i8(a, b, acc[f], 0, 0, 0);
    }
  }
  float wf = wfac[wfi];
  #pragma unroll
  for (int f=0; f<4; f++){
    int col = nb + f*16 + lr;
    float bval;
    if constexpr (MODE==0){
      int kv = col>>6, d = col&63;
      const float* bb = bias + kv*256 + d;
      bval = bb[0]+bb[64]+bb[128]+bb[192];
    } else {
      bval = bias[col];
    }
    #pragma unroll
    for (int r=0; r<4; r++){
      int row = mb + w*16 + lk*4 + r;
      float val = (float)acc[f][r] * (rowscale[row]*wf) + bval;
      if constexpr (MODE==0){
        ((unsigned short*)outp)[(size_t)row*KV_MODELC + col] = f2bf(0.125f*val);
      } else if constexpr (MODE==1){
        ((unsigned short*)outp)[(size_t)row*KV_MODELC + col] = f2bf(val);
      } else if constexpr (MODE==2){
        int bi = row>>11, s = row&2047;
        ((unsigned short*)outp)[((size_t)(bi*256 + col))*SEQ + s] = f2bf(val);
      } else {
        ((float*)outp)[(size_t)row*N_MODELC + col] = val;
      }
    }
  }
}

// ---------------- attention: energy + softmax, write probs f32 ---------------
__global__ __launch_bounds__(256) void k_attn(
    const unsigned short* __restrict__ Qs, const unsigned short* __restrict__ Kb,
    float* __restrict__ attn)
{
  int bkv = blockIdx.y, b = bkv>>2, kv = bkv&3;
  int rt = blockIdx.x;
  int w = threadIdx.x>>6, l = threadIdx.x&63, lr = l&15, lk = l>>4;
  int rowt = rt*64 + w*16;
  size_t tq = (size_t)(b*SEQ + rowt + lr)*KV_MODELC + kv*64 + lk*8;
  s16x8 qa0 = *reinterpret_cast<const s16x8*>(Qs + tq);
  s16x8 qa1 = *reinterpret_cast<const s16x8*>(Qs + tq + 32);
  const unsigned short* kbase = Kb + (size_t)b*SEQ*KV_MODELC + kv*64 + lk*8;
  float m[4], ll[4];
  #pragma unroll
  for (int r=0;r<4;r++){ m[r] = -INFINITY; ll[r] = 0.f; }
  for (int st=0; st<SEQ; st+=16){
    const unsigned short* kp = kbase + (size_t)(st+lr)*KV_MODELC;
    s16x8 k0 = *reinterpret_cast<const s16x8*>(kp);
    s16x8 k1 = *reinterpret_cast<const s16x8*>(kp + 32);
    f32x4 acc = {0.f,0.f,0.f,0.f};
    acc = __builtin_amdgcn_mfma_f32_16x16x32_bf16(qa0, k0, acc, 0,0,0);
    acc = __builtin_amdgcn_mfma_f32_16x16x32_bf16(qa1, k1, acc, 0,0,0);
    #pragma unroll
    for (int r=0;r<4;r++){
      float e = acc[r];
      float mn = fmaxf(m[r], e);
      ll[r] = ll[r]*__expf(m[r]-mn) + __expf(e-mn);
      m[r] = mn;
    }
  }
  #pragma unroll
  for (int r=0;r<4;r++){
    #pragma unroll
    for (int mask=1; mask<16; mask<<=1){
      float om = __shfl_xor(m[r], mask, 64);
      float ol = __shfl_xor(ll[r], mask, 64);
      float mn = fmaxf(m[r], om);
      ll[r] = ll[r]*__expf(m[r]-mn) + ol*__expf(om-mn);
      m[r] = mn;
    }
  }
  float invl[4];
  #pragma unroll
  for (int r=0;r<4;r++) invl[r] = 1.0f/ll[r];
  float* arow = attn + (size_t)bkv*SEQ*SEQ;
  for (int st=0; st<SEQ; st+=16){
    const unsigned short* kp = kbase + (size_t)(st+lr)*KV_MODELC;
    s16x8 k0 = *reinterpret_cast<const s16x8*>(kp);
    s16x8 k1 = *reinterpret_cast<const s16x8*>(kp + 32);
    f32x4 acc = {0.f,0.f,0.f,0.f};
    acc = __builtin_amdgcn_mfma_f32_16x16x32_bf16(qa0, k0, acc, 0,0,0);
    acc = __builtin_amdgcn_mfma_f32_16x16x32_bf16(qa1, k1, acc, 0,0,0);
    #pragma unroll
    for (int r=0;r<4;r++){
      float p = __expf(acc[r]-m[r])*invl[r];
      arow[(size_t)(rowt + lk*4 + r)*SEQ + st + lr] = p;
    }
  }
}

// ---------------- PV: x = attn @ V (bf16 MFMA), f32 out ----------------------
__global__ __launch_bounds__(256) void k_pv(
    const float* __restrict__ attn, const unsigned short* __restrict__ VT,
    float* __restrict__ X)
{
  int bkv = blockIdx.y, b = bkv>>2, kv = bkv&3;
  int nt = blockIdx.x;
  int w = threadIdx.x>>6, l = threadIdx.x&63, lr = l&15, lk = l>>4;
  int rowt = nt*64 + w*16;
  const float* arow = attn + (size_t)(bkv*SEQ + rowt + lr)*SEQ + lk*8;
  const unsigned short* vbase = VT + ((size_t)(b*256 + kv*64))*SEQ + lk*8;
  f32x4 acc[4];
  #pragma unroll
  for (int dt=0; dt<4; dt++) acc[dt] = f32x4{0.f,0.f,0.f,0.f};
  for (int sc=0; sc<SEQ; sc+=32){
    float4 a0 = *reinterpret_cast<const float4*>(arow + sc);
    float4 a1 = *reinterpret_cast<const float4*>(arow + sc + 4);
    s16x8 af;
    af[0]=(short)f2bf(a0.x); af[1]=(short)f2bf(a0.y);
    af[2]=(short)f2bf(a0.z); af[3]=(short)f2bf(a0.w);
    af[4]=(short)f2bf(a1.x); af[5]=(short)f2bf(a1.y);
    af[6]=(short)f2bf(a1.z); af[7]=(short)f2bf(a1.w);
    #pragma unroll
    for (int dt=0; dt<4; dt++){
      s16x8 bf = *reinterpret_cast<const s16x8*>(vbase + (size_t)(dt*16+lr)*SEQ + sc);
      acc[dt] = __builtin_amdgcn_mfma_f32_16x16x32_bf16(af, bf, acc[dt], 0,0,0);
    }
  }
  int token = b*SEQ + rowt + lk*4;
  #pragma unroll
  for (int dt=0; dt<4; dt++){
    #pragma unroll
    for (int r=0; r<4; r++){
      X[(size_t)(token + r)*KV_MODELC + kv*64 + dt*16 + lr] = acc[dt][r];
    }
  }
}

// -----------------------------------------------------------------------------
extern "C" void kernel_launch(void* const* d_in, const int* in_sizes, int n_in,
                              void* d_out, int out_size, void* d_ws, size_t ws_size,
                              hipStream_t stream)
{
  (void)in_sizes; (void)n_in; (void)out_size; (void)ws_size;
  const float* q  = (const float*)d_in[0];
  const float* k  = (const float*)d_in[1];
  const float* v  = (const float*)d_in[2];
  const float* Wq = (const float*)d_in[3];
  const float* bq = (const float*)d_in[4];
  const float* Wk = (const float*)d_in[5];
  const float* bk = (const float*)d_in[6];
  const float* Wv = (const float*)d_in[7];
  const float* bv = (const float*)d_in[8];
  const float* Wo = (const float*)d_in[9];
  const float* bo = (const float*)d_in[10];

  float* out_x = (float*)d_out;
  float* out_attn = out_x + (size_t)NTOK*N_MODELC;

  char* ws = (char*)d_ws;
  size_t off = 0;
  auto alloc = [&](size_t bytes)->void*{
    void* p = ws + off; off += (bytes + 255) & ~(size_t)255; return p;
  };
  int8_t* q8q = (int8_t*)alloc((size_t)NTOK*N_MODELC);
  int8_t* q8k = (int8_t*)alloc((size_t)NTOK*N_MODELC);
  int8_t* q8v = (int8_t*)alloc((size_t)NTOK*N_MODELC);
  int8_t* q8x = (int8_t*)alloc((size_t)NTOK*KV_MODELC);
  float* scq = (float*)alloc(NTOK*4);
  float* sck = (float*)alloc(NTOK*4);
  float* scv = (float*)alloc(NTOK*4);
  float* scx = (float*)alloc(NTOK*4);
  float* partial = (float*)alloc(4*256*4);
  float* wfac = (float*)alloc(256);
  int8_t* Wqs = (int8_t*)alloc(256*1024);
  int8_t* Wkt = (int8_t*)alloc(256*1024);
  int8_t* Wvt = (int8_t*)alloc(256*1024);
  int8_t* Wot = (int8_t*)alloc(1024*256);
  unsigned short* Qs = (unsigned short*)alloc((size_t)NTOK*KV_MODELC*2);
  unsigned short* Kb = (unsigned short*)alloc((size_t)NTOK*KV_MODELC*2);
  unsigned short* VT = (unsigned short*)alloc((size_t)NTOK*KV_MODELC*2);
  float* X = (float*)alloc((size_t)NTOK*KV_MODELC*4);

  // 1. act quant of q,k,v
  hipLaunchKernelGGL(k_actquant1024, dim3(NTOK,3), dim3(256), 0, stream,
                     q,k,v, q8q,q8k,q8v, scq,sck,scv);
  // 2-3. weight absmean
  hipLaunchKernelGGL(k_wabs_partial, dim3(256,4), dim3(256), 0, stream, Wq,Wk,Wv,Wo, partial);
  hipLaunchKernelGGL(k_wfinal, dim3(4), dim3(256), 0, stream, partial, wfac);
  // 4. ternarize
  hipLaunchKernelGGL(k_tern, dim3(1024,4), dim3(256), 0, stream,
                     Wq,Wk,Wv,Wo, wfac, Wqs,Wkt,Wvt,Wot);
  // 5-7. projections (int8 MFMA)
  hipLaunchKernelGGL((k_gemm_i8<1024,0>), dim3(128,4), dim3(256), 0, stream,
                     q8q, Wqs, scq, wfac, 0, bq, (void*)Qs);
  hipLaunchKernelGGL((k_gemm_i8<1024,1>), dim3(128,4), dim3(256), 0, stream,
                     q8k, Wkt, sck, wfac, 1, bk, (void*)Kb);
  hipLaunchKernelGGL((k_gemm_i8<1024,2>), dim3(128,4), dim3(256), 0, stream,
                     q8v, Wvt, scv, wfac, 2, bv, (void*)VT);
  // 8. attention energy + softmax -> d_out attn
  hipLaunchKernelGGL(k_attn, dim3(32,16), dim3(256), 0, stream, Qs, Kb, out_attn);
  // 9. PV
  hipLaunchKernelGGL(k_pv, dim3(32,16), dim3(256), 0, stream, out_attn, VT, X);
  // 10. act quant of x
  hipLaunchKernelGGL(k_actquant256, dim3(NTOK), dim3(64), 0, stream, X, q8x, scx);
  // 11. output bitlinear -> d_out x
  hipLaunchKernelGGL((k_gemm_i8<256,3>), dim3(128,16), dim3(256), 0, stream,
                     q8x, Wot, scx, wfac, 3, bo, (void*)out_x);
}

// Round 2
// 342.542 us; speedup vs baseline: 1.0967x; 1.0967x over previous
//
#include <hip/hip_runtime.h>
#include <stdint.h>

#define N_MODELC 1024
#define KV_MODELC 256
#define BATCH 4
#define SEQ 2048
#define NTOK (BATCH*SEQ)   // 8192

typedef __attribute__((ext_vector_type(4))) float f32x4;
typedef __attribute__((ext_vector_type(4))) int   i32x4;
typedef __attribute__((ext_vector_type(8))) short s16x8;

__device__ __forceinline__ unsigned short f2bf(float f){
  unsigned u = __builtin_bit_cast(unsigned, f);
  u = (u + 0x7FFFu + ((u>>16)&1u)) >> 16;
  return (unsigned short)u;
}

// ---------------- activation rmsnorm + int8 absmax quant (1024-wide rows) ----
__global__ __launch_bounds__(256) void k_actquant1024(
    const float* __restrict__ xq_in, const float* __restrict__ xk_in, const float* __restrict__ xv_in,
    int8_t* __restrict__ q8q, int8_t* __restrict__ q8k, int8_t* __restrict__ q8v,
    float* __restrict__ scq, float* __restrict__ sck, float* __restrict__ scv)
{
  int row = blockIdx.x, which = blockIdx.y, t = threadIdx.x;
  const float* x = (which==0)?xq_in:(which==1)?xk_in:xv_in;
  int8_t* q8 = (which==0)?q8q:(which==1)?q8k:q8v;
  float* sc = (which==0)?scq:(which==1)?sck:scv;
  const float* xr = x + (size_t)row*N_MODELC;
  float4 v = reinterpret_cast<const float4*>(xr)[t];
  float ss = v.x*v.x + v.y*v.y + v.z*v.z + v.w*v.w;
  float am = fmaxf(fmaxf(fabsf(v.x),fabsf(v.y)), fmaxf(fabsf(v.z),fabsf(v.w)));
  #pragma unroll
  for (int m=32;m;m>>=1){ ss += __shfl_xor(ss,m,64); am = fmaxf(am, __shfl_xor(am,m,64)); }
  __shared__ float red[8];
  int wid = t>>6;
  if ((t&63)==0){ red[wid]=ss; red[4+wid]=am; }
  __syncthreads();
  ss = red[0]+red[1]+red[2]+red[3];
  am = fmaxf(fmaxf(red[4],red[5]), fmaxf(red[6],red[7]));
  float rinv = rsqrtf(ss*(1.0f/N_MODELC) + 1e-6f);
  float clipv = fmaxf(am*rinv, 1e-5f);
  float qs = 127.0f/clipv;
  float fsc = rinv*qs;
  char4 o;
  o.x = (signed char)(int)fminf(127.f, fmaxf(-128.f, rintf(v.x*fsc)));
  o.y = (signed char)(int)fminf(127.f, fmaxf(-128.f, rintf(v.y*fsc)));
  o.z = (signed char)(int)fminf(127.f, fmaxf(-128.f, rintf(v.z*fsc)));
  o.w = (signed char)(int)fminf(127.f, fmaxf(-128.f, rintf(v.w*fsc)));
  reinterpret_cast<char4*>(q8 + (size_t)row*N_MODELC)[t] = o;
  if (t==0) sc[row] = clipv*(1.0f/127.0f);
}

// ---------------- same for 256-wide rows (one wave per row) ------------------
__global__ __launch_bounds__(64) void k_actquant256(
    const float* __restrict__ X, int8_t* __restrict__ q8, float* __restrict__ sc)
{
  int row = blockIdx.x, l = threadIdx.x;
  float4 v = reinterpret_cast<const float4*>(X + (size_t)row*KV_MODELC)[l];
  float ss = v.x*v.x + v.y*v.y + v.z*v.z + v.w*v.w;
  float am = fmaxf(fmaxf(fabsf(v.x),fabsf(v.y)), fmaxf(fabsf(v.z),fabsf(v.w)));
  #pragma unroll
  for (int m=32;m;m>>=1){ ss += __shfl_xor(ss,m,64); am = fmaxf(am, __shfl_xor(am,m,64)); }
  float rinv = rsqrtf(ss*(1.0f/KV_MODELC) + 1e-6f);
  float clipv = fmaxf(am*rinv, 1e-5f);
  float qs = 127.0f/clipv;
  float fsc = rinv*qs;
  char4 o;
  o.x = (signed char)(int)fminf(127.f, fmaxf(-128.f, rintf(v.x*fsc)));
  o.y = (signed char)(int)fminf(127.f, fmaxf(-128.f, rintf(v.y*fsc)));
  o.z = (signed char)(int)fminf(127.f, fmaxf(-128.f, rintf(v.z*fsc)));
  o.w = (signed char)(int)fminf(127.f, fmaxf(-128.f, rintf(v.w*fsc)));
  reinterpret_cast<char4*>(q8 + (size_t)row*KV_MODELC)[l] = o;
  if (l==0) sc[row] = clipv*(1.0f/127.0f);
}

// ---------------- weight absmean: stage 1 (deterministic partials) -----------
__global__ __launch_bounds__(256) void k_wabs_partial(
    const float* __restrict__ Wq, const float* __restrict__ Wk,
    const float* __restrict__ Wv, const float* __restrict__ Wo, float* __restrict__ partial)
{
  int mat = blockIdx.y;
  const float* w = (mat==0)?Wq:(mat==1)?Wk:(mat==2)?Wv:Wo;
  int n = (mat==0)?(N_MODELC*N_MODELC):(KV_MODELC*N_MODELC);
  float s = 0.f;
  for (int i = blockIdx.x*256 + threadIdx.x; i < n; i += 256*256) s += fabsf(w[i]);
  #pragma unroll
  for (int m=32;m;m>>=1) s += __shfl_xor(s,m,64);
  __shared__ float red[4];
  int wid = threadIdx.x>>6;
  if ((threadIdx.x&63)==0) red[wid]=s;
  __syncthreads();
  if (threadIdx.x==0) partial[mat*256 + blockIdx.x] = red[0]+red[1]+red[2]+red[3];
}

// ---------------- weight absmean: stage 2 ------------------------------------
__global__ __launch_bounds__(256) void k_wfinal(const float* __restrict__ partial, float* __restrict__ wfac)
{
  int mat = blockIdx.x, t = threadIdx.x;
  float s = partial[mat*256 + t];
  #pragma unroll
  for (int m=32;m;m>>=1) s += __shfl_xor(s,m,64);
  __shared__ float red[4];
  int wid = t>>6;
  if ((t&63)==0) red[wid]=s;
  __syncthreads();
  if (t==0){
    float tot = red[0]+red[1]+red[2]+red[3];
    float n = (mat==0)?(float)(N_MODELC*N_MODELC):(float)(KV_MODELC*N_MODELC);
    wfac[mat] = fmaxf(tot/n, 1e-5f);   // = 1/scale (dequant factor)
  }
}

// ---------------- ternarize weights (Wq also group-summed) -------------------
__global__ __launch_bounds__(256) void k_tern(
    const float* __restrict__ Wq, const float* __restrict__ Wk,
    const float* __restrict__ Wv, const float* __restrict__ Wo,
    const float* __restrict__ wfac,
    int8_t* __restrict__ Wqs, int8_t* __restrict__ Wkt,
    int8_t* __restrict__ Wvt, int8_t* __restrict__ Wot)
{
  int mat = blockIdx.y;
  int idx = blockIdx.x*256 + threadIdx.x;   // < 262144
  if (mat==0){
    float s = 1.0f/wfac[0];
    int op = idx>>10, i = idx&1023;
    int kv = op>>6, d = op&63;
    int acc = 0;
    #pragma unroll
    for (int g=0; g<4; g++){
      float w = Wq[(size_t)(kv*256 + g*64 + d)*N_MODELC + i];
      float r = fminf(1.f, fmaxf(-1.f, rintf(w*s)));
      acc += (int)r;
    }
    Wqs[idx] = (int8_t)acc;
  } else {
    const float* w = (mat==1)?Wk:(mat==2)?Wv:Wo;
    int8_t* o = (mat==1)?Wkt:(mat==2)?Wvt:Wot;
    float s = 1.0f/wfac[mat];
    float r = fminf(1.f, fmaxf(-1.f, rintf(w[idx]*s)));
    o[idx] = (int8_t)r;
  }
}

// ---------------- int8 GEMM: C = A[M,K] x B[N,K]^T, dequant epilogue ---------
// MODE 0: Qsum -> bf16 [M,256], x0.125, group-summed bias
// MODE 1: K    -> bf16 [M,256]
// MODE 2: V    -> bf16 transposed VT[(b*256+col), s]
// MODE 3: O    -> f32 [M,1024] to d_out
template<int KDIM, int MODE>
__global__ __launch_bounds__(256) void k_gemm_i8(
    const int8_t* __restrict__ A, const int8_t* __restrict__ B,
    const float* __restrict__ rowscale, const float* __restrict__ wfac, int wfi,
    const float* __restrict__ bias, void* __restrict__ outp)
{
  int mb = blockIdx.x*64, nb = blockIdx.y*64;
  int w = threadIdx.x>>6, l = threadIdx.x&63, lr = l&15, lk = l>>4;
  const int8_t* Ap = A + (size_t)(mb + w*16 + lr)*KDIM + lk*16;
  const int8_t* Bp = B + (size_t)(nb + lr)*KDIM + lk*16;
  i32x4 acc[4];
  #pragma unroll
  for (int f=0; f<4; f++) acc[f] = i32x4{0,0,0,0};
  #pragma unroll 4
  for (int kk=0; kk<KDIM; kk+=64){
    i32x4 a = *reinterpret_cast<const i32x4*>(Ap + kk);
    #pragma unroll
    for (int f=0; f<4; f++){
      i32x4 b = *reinterpret_cast<const i32x4*>(Bp + (size_t)f*16*KDIM + kk);
      acc[f] = __builtin_amdgcn_mfma_i32_16x16x64_i8(a, b, acc[f], 0, 0, 0);
    }
  }
  float wf = wfac[wfi];
  #pragma unroll
  for (int f=0; f<4; f++){
    int col = nb + f*16 + lr;
    float bval;
    if constexpr (MODE==0){
      int kv = col>>6, d = col&63;
      const float* bb = bias + kv*256 + d;
      bval = bb[0]+bb[64]+bb[128]+bb[192];
    } else {
      bval = bias[col];
    }
    #pragma unroll
    for (int r=0; r<4; r++){
      int row = mb + w*16 + lk*4 + r;
      float val = (float)acc[f][r] * (rowscale[row]*wf) + bval;
      if constexpr (MODE==0){
        ((unsigned short*)outp)[(size_t)row*KV_MODELC + col] = f2bf(0.125f*val);
      } else if constexpr (MODE==1){
        ((unsigned short*)outp)[(size_t)row*KV_MODELC + col] = f2bf(val);
      } else if constexpr (MODE==2){
        int bi = row>>11, s = row&2047;
        ((unsigned short*)outp)[((size_t)(bi*256 + col))*SEQ + s] = f2bf(val);
      } else {
        ((float*)outp)[(size_t)row*N_MODELC + col] = val;
      }
    }
  }
}

// ---------------- fused attention: energy + softmax + probs write + PV -------
// Block: 4 waves, 64 q-rows, one (b,kv). Wave w owns q rows [w*16, w*16+16).
// Pass 1: online (m,l) over all s via MFMA energy tiles.
// Pass 2: recompute energy, write normalized probs f32 to attn (d_out), stash
//         bf16 P in wave-private LDS (XOR chunk swizzle), accumulate PV from
//         LDS (A) x VT global (B, L2-resident). No __syncthreads needed: LDS
//         regions are wave-private.
__global__ __launch_bounds__(256) void k_attn_pv(
    const unsigned short* __restrict__ Qs, const unsigned short* __restrict__ Kb,
    const unsigned short* __restrict__ VT,
    float* __restrict__ attn, float* __restrict__ X)
{
  __shared__ unsigned short plds[64][64];   // [q][s-chunk swizzled], 8 KB
  int bkv = blockIdx.y, b = bkv>>2, kv = bkv&3;
  int w = threadIdx.x>>6, l = threadIdx.x&63, lr = l&15, lk = l>>4;
  int brow = blockIdx.x*64;            // block's first q row
  int rowt = brow + w*16;              // wave's first q row
  size_t tq = (size_t)(b*SEQ + rowt + lr)*KV_MODELC + kv*64 + lk*8;
  s16x8 qa0 = *reinterpret_cast<const s16x8*>(Qs + tq);
  s16x8 qa1 = *reinterpret_cast<const s16x8*>(Qs + tq + 32);
  const unsigned short* kbase = Kb + (size_t)b*SEQ*KV_MODELC + kv*64 + lk*8;
  const unsigned short* vbase = VT + ((size_t)(b*256 + kv*64))*SEQ;

  // ---- pass 1: online max/sum ----
  float m[4], ll[4];
  #pragma unroll
  for (int r=0;r<4;r++){ m[r] = -INFINITY; ll[r] = 0.f; }
  for (int st=0; st<SEQ; st+=16){
    const unsigned short* kp = kbase + (size_t)(st+lr)*KV_MODELC;
    s16x8 k0 = *reinterpret_cast<const s16x8*>(kp);
    s16x8 k1 = *reinterpret_cast<const s16x8*>(kp + 32);
    f32x4 acc = {0.f,0.f,0.f,0.f};
    acc = __builtin_amdgcn_mfma_f32_16x16x32_bf16(qa0, k0, acc, 0,0,0);
    acc = __builtin_amdgcn_mfma_f32_16x16x32_bf16(qa1, k1, acc, 0,0,0);
    #pragma unroll
    for (int r=0;r<4;r++){
      float e = acc[r];
      float mn = fmaxf(m[r], e);
      ll[r] = ll[r]*__expf(m[r]-mn) + __expf(e-mn);
      m[r] = mn;
    }
  }
  #pragma unroll
  for (int r=0;r<4;r++){
    #pragma unroll
    for (int mask=1; mask<16; mask<<=1){
      float om = __shfl_xor(m[r], mask, 64);
      float ol = __shfl_xor(ll[r], mask, 64);
      float mn = fmaxf(m[r], om);
      ll[r] = ll[r]*__expf(m[r]-mn) + ol*__expf(om-mn);
      m[r] = mn;
    }
  }
  float invl[4];
  #pragma unroll
  for (int r=0;r<4;r++) invl[r] = 1.0f/ll[r];

  // ---- pass 2: probs write + PV accumulate ----
  float* arow = attn + (size_t)bkv*SEQ*SEQ + (size_t)brow*SEQ;
  f32x4 acco[4];
  #pragma unroll
  for (int dt=0; dt<4; dt++) acco[dt] = f32x4{0.f,0.f,0.f,0.f};
  int qw = w*16 + lk*4;                 // write-side q rows (+r)
  int qr = w*16 + lr;                   // read-side q row for PV A-frag
  int rsw = (qr&7)<<3;                  // read swizzle base

  for (int st=0; st<SEQ; st+=64){
    #pragma unroll
    for (int sub=0; sub<4; sub++){
      int s0 = st + sub*16;
      const unsigned short* kp = kbase + (size_t)(s0+lr)*KV_MODELC;
      s16x8 k0 = *reinterpret_cast<const s16x8*>(kp);
      s16x8 k1 = *reinterpret_cast<const s16x8*>(kp + 32);
      f32x4 acc = {0.f,0.f,0.f,0.f};
      acc = __builtin_amdgcn_mfma_f32_16x16x32_bf16(qa0, k0, acc, 0,0,0);
      acc = __builtin_amdgcn_mfma_f32_16x16x32_bf16(qa1, k1, acc, 0,0,0);
      int slocal = sub*16 + lr;
      #pragma unroll
      for (int r=0;r<4;r++){
        float p = __expf(acc[r]-m[r])*invl[r];
        arow[(size_t)(qw + r)*SEQ + s0 + lr] = p;
        int sw = (slocal & 7) | ((((slocal>>3) ^ ((qw+r)&7)))<<3);
        plds[qw + r][sw] = f2bf(p);
      }
    }
    // PV over this 64-s block (wave-private LDS; compiler inserts lgkmcnt)
    s16x8 a0 = *reinterpret_cast<const s16x8*>(&plds[qr][lk<<3 ^ rsw]);
    s16x8 a1 = *reinterpret_cast<const s16x8*>(&plds[qr][(4+lk)<<3 ^ rsw]);
    #pragma unroll
    for (int dt=0; dt<4; dt++){
      const unsigned short* vp = vbase + (size_t)(dt*16+lr)*SEQ + st + lk*8;
      s16x8 b0 = *reinterpret_cast<const s16x8*>(vp);
      s16x8 b1 = *reinterpret_cast<const s16x8*>(vp + 32);
      acco[dt] = __builtin_amdgcn_mfma_f32_16x16x32_bf16(a0, b0, acco[dt], 0,0,0);
      acco[dt] = __builtin_amdgcn_mfma_f32_16x16x32_bf16(a1, b1, acco[dt], 0,0,0);
    }
  }
  // epilogue: X[token][kv*64 + d]
  int token = b*SEQ + rowt + lk*4;
  #pragma unroll
  for (int dt=0; dt<4; dt++){
    #pragma unroll
    for (int r=0; r<4; r++){
      X[(size_t)(token + r)*KV_MODELC + kv*64 + dt*16 + lr] = acco[dt][r];
    }
  }
}

// -----------------------------------------------------------------------------
extern "C" void kernel_launch(void* const* d_in, const int* in_sizes, int n_in,
                              void* d_out, int out_size, void* d_ws, size_t ws_size,
                              hipStream_t stream)
{
  (void)in_sizes; (void)n_in; (void)out_size; (void)ws_size;
  const float* q  = (const float*)d_in[0];
  const float* k  = (const float*)d_in[1];
  const float* v  = (const float*)d_in[2];
  const float* Wq = (const float*)d_in[3];
  const float* bq = (const float*)d_in[4];
  const float* Wk = (const float*)d_in[5];
  const float* bk = (const float*)d_in[6];
  const float* Wv = (const float*)d_in[7];
  const float* bv = (const float*)d_in[8];
  const float* Wo = (const float*)d_in[9];
  const float* bo = (const float*)d_in[10];

  float* out_x = (float*)d_out;
  float* out_attn = out_x + (size_t)NTOK*N_MODELC;

  char* ws = (char*)d_ws;
  size_t off = 0;
  auto alloc = [&](size_t bytes)->void*{
    void* p = ws + off; off += (bytes + 255) & ~(size_t)255; return p;
  };
  int8_t* q8q = (int8_t*)alloc((size_t)NTOK*N_MODELC);
  int8_t* q8k = (int8_t*)alloc((size_t)NTOK*N_MODELC);
  int8_t* q8v = (int8_t*)alloc((size_t)NTOK*N_MODELC);
  int8_t* q8x = (int8_t*)alloc((size_t)NTOK*KV_MODELC);
  float* scq = (float*)alloc(NTOK*4);
  float* sck = (float*)alloc(NTOK*4);
  float* scv = (float*)alloc(NTOK*4);
  float* scx = (float*)alloc(NTOK*4);
  float* partial = (float*)alloc(4*256*4);
  float* wfac = (float*)alloc(256);
  int8_t* Wqs = (int8_t*)alloc(256*1024);
  int8_t* Wkt = (int8_t*)alloc(256*1024);
  int8_t* Wvt = (int8_t*)alloc(256*1024);
  int8_t* Wot = (int8_t*)alloc(1024*256);
  unsigned short* Qs = (unsigned short*)alloc((size_t)NTOK*KV_MODELC*2);
  unsigned short* Kb = (unsigned short*)alloc((size_t)NTOK*KV_MODELC*2);
  unsigned short* VT = (unsigned short*)alloc((size_t)NTOK*KV_MODELC*2);
  float* X = (float*)alloc((size_t)NTOK*KV_MODELC*4);

  // 1. act quant of q,k,v
  hipLaunchKernelGGL(k_actquant1024, dim3(NTOK,3), dim3(256), 0, stream,
                     q,k,v, q8q,q8k,q8v, scq,sck,scv);
  // 2-3. weight absmean
  hipLaunchKernelGGL(k_wabs_partial, dim3(256,4), dim3(256), 0, stream, Wq,Wk,Wv,Wo, partial);
  hipLaunchKernelGGL(k_wfinal, dim3(4), dim3(256), 0, stream, partial, wfac);
  // 4. ternarize
  hipLaunchKernelGGL(k_tern, dim3(1024,4), dim3(256), 0, stream,
                     Wq,Wk,Wv,Wo, wfac, Wqs,Wkt,Wvt,Wot);
  // 5-7. projections (int8 MFMA)
  hipLaunchKernelGGL((k_gemm_i8<1024,0>), dim3(128,4), dim3(256), 0, stream,
                     q8q, Wqs, scq, wfac, 0, bq, (void*)Qs);
  hipLaunchKernelGGL((k_gemm_i8<1024,1>), dim3(128,4), dim3(256), 0, stream,
                     q8k, Wkt, sck, wfac, 1, bk, (void*)Kb);
  hipLaunchKernelGGL((k_gemm_i8<1024,2>), dim3(128,4), dim3(256), 0, stream,
                     q8v, Wvt, scv, wfac, 2, bv, (void*)VT);
  // 8. fused attention energy + softmax + probs + PV
  hipLaunchKernelGGL(k_attn_pv, dim3(32,16), dim3(256), 0, stream,
                     Qs, Kb, VT, out_attn, X);
  // 9. act quant of x
  hipLaunchKernelGGL(k_actquant256, dim3(NTOK), dim3(64), 0, stream, X, q8x, scx);
  // 10. output bitlinear -> d_out x
  hipLaunchKernelGGL((k_gemm_i8<256,3>), dim3(128,16), dim3(256), 0, stream,
                     q8x, Wot, scx, wfac, 3, bo, (void*)out_x);
}